// Round 4
// baseline (309.424 us; speedup 1.0000x reference)
//
#include <hip/hip_runtime.h>

// Problem constants (fixed by setup_inputs): B=128, C=3, N=320
constexpr int B    = 128;
constexpr int C    = 3;
constexpr int N    = 320;
constexpr int G    = N * N;        // 102400 elements per (b, c) plane
constexpr int G4   = G / 4;        // 25600 float4 chunks per plane
constexpr int ROW4 = N / 4;        // 80 float4 chunks per row
constexpr int BLOCKS  = 1600;      // 1600*256 = 409600 = 16 * G4 -> q invariant per thread
constexpr int THREADS = 256;
constexpr int BSTEP   = (BLOCKS * THREADS) / G4;  // 16 batches covered per sweep
constexpr int ITERS   = B / BSTEP;                // 8 iterations, exact
constexpr unsigned long long TOTAL_EDGES =
    (unsigned long long)B * (unsigned long long)(N * (N - 1) / 2); // 6,533,120

// Fused kernel: count + device-wide reduce + last-block-done finalize.
// ws[0] = global count accumulator, ws[1] = completion ticket (both memset to 0).
__global__ __launch_bounds__(THREADS) void edge_acc_kernel(
    const float* __restrict__ inp,      // [B, C, G] float32
    const int*   __restrict__ tgt,      // [B, G] int32
    unsigned int* __restrict__ ws,      // [2] zero-initialized by memset node
    float* __restrict__ out)
{
    const int tid = blockIdx.x * THREADS + threadIdx.x;   // 0 .. 409599
    const int q   = tid % G4;            // chunk within a plane (loop-invariant)
    const int b0  = tid / G4;            // 0 .. 15
    const int i   = q / ROW4;            // row in N x N
    const int jb  = (q - i * ROW4) * 4;  // first column of this chunk

    unsigned int cnt = 0;

    // Strict upper triangle: j > i. Whole-chunk skip decided ONCE per thread;
    // all 8 batch iterations share the same (i, jb) -> 32 independent loads
    // in flight for active threads (MLP for HBM latency hiding).
    if (jb + 3 > i) {
        const unsigned m0 = (unsigned)(jb + 0 > i);
        const unsigned m1 = (unsigned)(jb + 1 > i);
        const unsigned m2 = (unsigned)(jb + 2 > i);
        const size_t gofs = (size_t)q * 4;

        #pragma unroll
        for (int it = 0; it < ITERS; ++it) {
            const int b = b0 + BSTEP * it;
            const float* p = inp + (size_t)b * (C * G) + gofs;

            const float4 x0 = *(const float4*)(p);
            const float4 x1 = *(const float4*)(p + G);
            const float4 x2 = *(const float4*)(p + 2 * G);
            const int4   tv = *(const int4*)(tgt + (size_t)b * G + gofs);

            // first-occurrence argmax over C=3 (matches jnp.argmax ties)
            {
                int pred = 0; float m = x0.x;
                if (x1.x > m) { m = x1.x; pred = 1; }
                if (x2.x > m) { pred = 2; }
                cnt += m0 & (unsigned)(pred == tv.x);
            }
            {
                int pred = 0; float m = x0.y;
                if (x1.y > m) { m = x1.y; pred = 1; }
                if (x2.y > m) { pred = 2; }
                cnt += m1 & (unsigned)(pred == tv.y);
            }
            {
                int pred = 0; float m = x0.z;
                if (x1.z > m) { m = x1.z; pred = 1; }
                if (x2.z > m) { pred = 2; }
                cnt += m2 & (unsigned)(pred == tv.z);
            }
            {
                int pred = 0; float m = x0.w;
                if (x1.w > m) { m = x1.w; pred = 1; }
                if (x2.w > m) { pred = 2; }
                cnt += (unsigned)(pred == tv.w);   // jb+3 > i guaranteed here
            }
        }
    }

    // ---- wave (64-lane shuffle) -> block (LDS) -> one atomic per block ----
    #pragma unroll
    for (int off = 32; off > 0; off >>= 1)
        cnt += __shfl_down(cnt, off, 64);

    __shared__ unsigned int wsum[THREADS / 64];
    const int lane = threadIdx.x & 63;
    const int wave = threadIdx.x >> 6;
    if (lane == 0) wsum[wave] = cnt;
    __syncthreads();

    if (threadIdx.x == 0) {
        const unsigned int bsum = wsum[0] + wsum[1] + wsum[2] + wsum[3];
        atomicAdd(&ws[0], bsum);              // device-scope by default
        __threadfence();                      // count-add visible before ticket-add
        const unsigned int ticket = atomicAdd(&ws[1], 1u);
        if (ticket == (unsigned)(BLOCKS - 1)) {
            // Last block to finish: all 1600 count-adds are ordered before their
            // ticket-adds (fence above), so an atomic read here sees the total.
            __threadfence();
            const unsigned int total = atomicAdd(&ws[0], 0u);  // RMW read, bypasses L1
            out[0] = 1.0f - (float)((double)total / (double)TOTAL_EDGES);
        }
    }
}

extern "C" void kernel_launch(void* const* d_in, const int* in_sizes, int n_in,
                              void* d_out, int out_size, void* d_ws, size_t ws_size,
                              hipStream_t stream) {
    const float* inp = (const float*)d_in[0];
    const int*   tgt = (const int*)d_in[1];
    float*       out = (float*)d_out;
    unsigned int* ws = (unsigned int*)d_ws;   // 8 bytes used

    // d_ws is re-poisoned to 0xAA before every timed launch -> zero the two
    // accumulator words (tiny fill node; removes the dependent finalize kernel).
    hipMemsetAsync(ws, 0, 2 * sizeof(unsigned int), stream);
    edge_acc_kernel<<<BLOCKS, THREADS, 0, stream>>>(inp, tgt, ws, out);
}

// Round 5
// 234.511 us; speedup vs baseline: 1.3194x; 1.3194x over previous
//
#include <hip/hip_runtime.h>

// Problem constants (fixed by setup_inputs): B=128, C=3, N=320
constexpr int B    = 128;
constexpr int C    = 3;
constexpr int N    = 320;
constexpr int G    = N * N;        // 102400 elements per (b, c) plane
constexpr int G4   = G / 4;        // 25600 float4 chunks per plane
constexpr int ROW4 = N / 4;        // 80 float4 chunks per row
constexpr int BLOCKS  = 1600;      // 1600*256 = 409600 = 16 * G4 -> q invariant per thread
constexpr int THREADS = 256;
constexpr int BSTEP   = (BLOCKS * THREADS) / G4;  // 16 batches covered per sweep
constexpr int ITERS   = B / BSTEP;                // 8 iterations, exact
constexpr unsigned long long TOTAL_EDGES =
    (unsigned long long)B * (unsigned long long)(N * (N - 1) / 2); // 6,533,120

// __launch_bounds__(256, 4): allow up to ~128 VGPRs (round-4 showed the
// default allocator picked 32 -> one iteration's loads couldn't stay in
// flight). 4 waves/SIMD = 16 waves/CU is plenty for a BW-bound stream.
__global__ __launch_bounds__(THREADS, 4) void edge_acc_kernel(
    const float* __restrict__ inp,      // [B, C, G] float32
    const int*   __restrict__ tgt,      // [B, G] int32
    unsigned int* __restrict__ partials) // [BLOCKS], plain stores (no init needed)
{
    const int tid = blockIdx.x * THREADS + threadIdx.x;   // 0 .. 409599
    const int q   = tid % G4;            // chunk within a plane (loop-invariant)
    const int b0  = tid / G4;            // 0 .. 15
    const int i   = q / ROW4;            // row in N x N
    const int jb  = (q - i * ROW4) * 4;  // first column of this chunk

    unsigned int cnt = 0;

    // Strict upper triangle: j > i. Whole-chunk skip decided ONCE per thread.
    if (jb + 3 > i) {
        const unsigned m0 = (unsigned)(jb + 0 > i);
        const unsigned m1 = (unsigned)(jb + 1 > i);
        const unsigned m2 = (unsigned)(jb + 2 > i);
        const size_t gofs  = (size_t)q * 4;
        const float* pbase = inp + gofs;
        const int*   tbase = tgt + gofs;

        // 2-deep software pipeline: iteration it+1's 4 vector loads are issued
        // before consuming iteration it -> ~8 wave-loads in flight instead of 4,
        // and the waitcnt before consumption no longer drains the next loads.
        float4 x0 = *(const float4*)(pbase + (size_t)b0 * (C * G));
        float4 x1 = *(const float4*)(pbase + (size_t)b0 * (C * G) + G);
        float4 x2 = *(const float4*)(pbase + (size_t)b0 * (C * G) + 2 * G);
        int4   tv = *(const int4*)(tbase + (size_t)b0 * G);

        #pragma unroll
        for (int it = 0; it < ITERS; ++it) {
            float4 n0, n1, n2; int4 ntv;
            if (it + 1 < ITERS) {
                const int b = b0 + BSTEP * (it + 1);
                const float* p = pbase + (size_t)b * (C * G);
                n0  = *(const float4*)(p);
                n1  = *(const float4*)(p + G);
                n2  = *(const float4*)(p + 2 * G);
                ntv = *(const int4*)(tbase + (size_t)b * G);
            }

            // first-occurrence argmax over C=3 (matches jnp.argmax ties)
            {
                int pred = 0; float m = x0.x;
                if (x1.x > m) { m = x1.x; pred = 1; }
                if (x2.x > m) { pred = 2; }
                cnt += m0 & (unsigned)(pred == tv.x);
            }
            {
                int pred = 0; float m = x0.y;
                if (x1.y > m) { m = x1.y; pred = 1; }
                if (x2.y > m) { pred = 2; }
                cnt += m1 & (unsigned)(pred == tv.y);
            }
            {
                int pred = 0; float m = x0.z;
                if (x1.z > m) { m = x1.z; pred = 1; }
                if (x2.z > m) { pred = 2; }
                cnt += m2 & (unsigned)(pred == tv.z);
            }
            {
                int pred = 0; float m = x0.w;
                if (x1.w > m) { m = x1.w; pred = 1; }
                if (x2.w > m) { pred = 2; }
                cnt += (unsigned)(pred == tv.w);   // jb+3 > i guaranteed here
            }

            if (it + 1 < ITERS) { x0 = n0; x1 = n1; x2 = n2; tv = ntv; }
        }
    }

    // ---- wave (64-lane shuffle) -> block (LDS) -> one plain store per block ----
    #pragma unroll
    for (int off = 32; off > 0; off >>= 1)
        cnt += __shfl_down(cnt, off, 64);

    __shared__ unsigned int wsum[THREADS / 64];
    const int lane = threadIdx.x & 63;
    const int wave = threadIdx.x >> 6;
    if (lane == 0) wsum[wave] = cnt;
    __syncthreads();

    if (threadIdx.x == 0)
        partials[blockIdx.x] = wsum[0] + wsum[1] + wsum[2] + wsum[3];
}

// Single-wave finalize: no LDS, no __syncthreads, uint4 partial reads.
__global__ __launch_bounds__(64) void finalize_kernel(
    const unsigned int* __restrict__ partials,  // [BLOCKS], BLOCKS % 4 == 0
    float* __restrict__ out)
{
    unsigned int s = 0;
    const uint4* p4 = (const uint4*)partials;
    for (int idx = threadIdx.x; idx < BLOCKS / 4; idx += 64) {
        const uint4 v = p4[idx];
        s += v.x + v.y + v.z + v.w;
    }

    #pragma unroll
    for (int off = 32; off > 0; off >>= 1)
        s += __shfl_down(s, off, 64);

    if (threadIdx.x == 0)
        out[0] = 1.0f - (float)((double)s / (double)TOTAL_EDGES);
}

extern "C" void kernel_launch(void* const* d_in, const int* in_sizes, int n_in,
                              void* d_out, int out_size, void* d_ws, size_t ws_size,
                              hipStream_t stream) {
    const float* inp = (const float*)d_in[0];
    const int*   tgt = (const int*)d_in[1];
    float*       out = (float*)d_out;
    unsigned int* partials = (unsigned int*)d_ws;  // BLOCKS * 4 bytes used

    edge_acc_kernel<<<BLOCKS, THREADS, 0, stream>>>(inp, tgt, partials);
    finalize_kernel<<<1, 64, 0, stream>>>(partials, out);
}